// Round 2
// baseline (126897.949 us; speedup 1.0000x reference)
//
#include <hip/hip_runtime.h>
#include <hip/hip_cooperative_groups.h>
#include <cmath>

namespace cg = cooperative_groups;

// Problem constants (setup_inputs): B=64, S=1024, I=1024, H=1024, fp32.
constexpr int B = 64, S = 1024, I = 1024, H = 1024;
constexpr int KS = 16;   // k-chunks of 64 (scan K-split)

// ---------------------------------------------------------------------------
// Phase 1: wx[m,n] = sum_k x[m,k] * Wih_w[n,k] + Wih_b[n]   (NT GEMM, fp32)
// ---------------------------------------------------------------------------
__global__ __launch_bounds__(256) void gemm_nt(
    const float* __restrict__ A, const float* __restrict__ W,
    const float* __restrict__ bias, float* __restrict__ C) {
  __shared__ float As[16][68];
  __shared__ float Bs[16][68];
  const int tid = threadIdx.x;
  const int m0 = blockIdx.y * 64;
  const int n0 = blockIdx.x * 64;
  const int tx = tid & 15;
  const int ty = tid >> 4;
  const int lr = tid >> 2;
  const int lc = (tid & 3) * 4;

  const float* Ap = A + (size_t)(m0 + lr) * I + lc;
  const float* Wp = W + (size_t)(n0 + lr) * I + lc;

  float acc[4][4] = {};
  for (int k0 = 0; k0 < I; k0 += 16) {
    float4 av = *(const float4*)(Ap + k0);
    float4 wv = *(const float4*)(Wp + k0);
    As[lc + 0][lr] = av.x; As[lc + 1][lr] = av.y;
    As[lc + 2][lr] = av.z; As[lc + 3][lr] = av.w;
    Bs[lc + 0][lr] = wv.x; Bs[lc + 1][lr] = wv.y;
    Bs[lc + 2][lr] = wv.z; Bs[lc + 3][lr] = wv.w;
    __syncthreads();
#pragma unroll
    for (int kk = 0; kk < 16; ++kk) {
      float4 a = *(const float4*)&As[kk][ty * 4];
      float4 b = *(const float4*)&Bs[kk][tx * 4];
      float ar[4] = {a.x, a.y, a.z, a.w};
      float br[4] = {b.x, b.y, b.z, b.w};
#pragma unroll
      for (int i = 0; i < 4; ++i)
#pragma unroll
        for (int j = 0; j < 4; ++j) acc[i][j] += ar[i] * br[j];
    }
    __syncthreads();
  }
  float bj[4];
#pragma unroll
  for (int j = 0; j < 4; ++j) bj[j] = bias[n0 + tx * 4 + j];
#pragma unroll
  for (int i = 0; i < 4; ++i) {
    int m = m0 + ty * 4 + i;
    float4 o = make_float4(acc[i][0] + bj[0], acc[i][1] + bj[1],
                           acc[i][2] + bj[2], acc[i][3] + bj[3]);
    *(float4*)&C[(size_t)m * H + n0 + tx * 4] = o;
  }
}

// ---------------------------------------------------------------------------
// Persistent cooperative scan. 256 blocks: c = k-chunk (16), g = g-tile (16).
// Whh tile resident in LDS for all 1024 steps. h_t lives in y[:, t, :].
// Per step: GEMM partial -> P, grid.sync, reduce+tanh -> y, grid.sync,
// reload A-slice (h) into LDS.
// ---------------------------------------------------------------------------
__global__ __launch_bounds__(256) void rnn_scan(
    const float* __restrict__ h0, const float* __restrict__ Whh,
    const float* __restrict__ bias, float* __restrict__ y,
    float* __restrict__ hlast, float* __restrict__ P) {
  cg::grid_group grid = cg::this_grid();
  __shared__ float Ws[64][68];   // Ws[kk][gg] = Whh[g0+gg][k0+kk]
  __shared__ float Hs[64][68];   // Hs[kk][bb] = h_t[bb][k0+kk]
  const int tid = threadIdx.x;
  const int c = blockIdx.x & 15;
  const int g = blockIdx.x >> 4;
  const int g0 = g * 64, k0 = c * 64;
  const int tx = tid & 15;
  const int ty = tid >> 4;

  // Load Whh tile once (resident across all timesteps).
  {
    const int r = tid >> 4;          // 0..15
    const int cc = (tid & 15) * 4;   // kk base
#pragma unroll
    for (int p = 0; p < 4; ++p) {
      const int gg = r + p * 16;
      float4 wv = *(const float4*)(Whh + (size_t)(g0 + gg) * H + k0 + cc);
      Ws[cc + 0][gg] = wv.x; Ws[cc + 1][gg] = wv.y;
      Ws[cc + 2][gg] = wv.z; Ws[cc + 3][gg] = wv.w;
    }
  }
  // Initial A-slice from h0: Hs[kk][bb] = h0[bb][k0+kk]
  {
    const int f = (tid & 15) * 4;
    const int bbase = tid >> 4;
#pragma unroll
    for (int p = 0; p < 4; ++p) {
      const int bb = bbase + p * 16;
      float4 hv = *(const float4*)(h0 + (size_t)bb * H + k0 + f);
      Hs[f + 0][bb] = hv.x; Hs[f + 1][bb] = hv.y;
      Hs[f + 2][bb] = hv.z; Hs[f + 3][bb] = hv.w;
    }
  }
  __syncthreads();

  // Reduce-phase fixed mapping: this block reduces rows bb=g*4..g*4+3 of
  // h-slice [:, k0:k0+64]; one element per thread.
  const int rgg = tid & 63;
  const int rbb = g * 4 + (tid >> 6);
  const int rcol = k0 + rgg;
  const float rbias = bias[rcol];

  for (int t = 0; t < S; ++t) {
    // --- GEMM partial: P[c][bb][g0+gg] = sum_kk Hs[kk][bb] * Ws[kk][gg] ---
    float acc[4][4] = {};
#pragma unroll 16
    for (int kk = 0; kk < 64; ++kk) {
      float4 hb = *(const float4*)&Hs[kk][ty * 4];
      float4 wb = *(const float4*)&Ws[kk][tx * 4];
      float hr[4] = {hb.x, hb.y, hb.z, hb.w};
      float wr[4] = {wb.x, wb.y, wb.z, wb.w};
#pragma unroll
      for (int i = 0; i < 4; ++i)
#pragma unroll
        for (int j = 0; j < 4; ++j) acc[i][j] += hr[i] * wr[j];
    }
#pragma unroll
    for (int i = 0; i < 4; ++i) {
      const int bb = ty * 4 + i;
      float4 o = make_float4(acc[i][0], acc[i][1], acc[i][2], acc[i][3]);
      *(float4*)&P[((size_t)c * B + bb) * H + g0 + tx * 4] = o;
    }
    __threadfence();
    grid.sync();

    // --- Reduce + bias + wx + tanh -> y[:, t, :] (h_{t+1}) ---
    {
      const size_t yoff = ((size_t)rbb * S + t) * H + rcol;
      float v = y[yoff] + rbias;
#pragma unroll
      for (int cp = 0; cp < KS; ++cp)
        v += P[((size_t)cp * B + rbb) * H + rcol];
      v = tanhf(v);
      y[yoff] = v;
      if (t == S - 1) hlast[(size_t)rbb * H + rcol] = v;
    }
    __threadfence();
    grid.sync();

    // --- Reload A-slice for next step: Hs[kk][bb] = y[bb][t][k0+kk] ---
    if (t < S - 1) {
      const int f = (tid & 15) * 4;
      const int bbase = tid >> 4;
#pragma unroll
      for (int p = 0; p < 4; ++p) {
        const int bb = bbase + p * 16;
        float4 hv = *(const float4*)(y + ((size_t)bb * S + t) * H + k0 + f);
        Hs[f + 0][bb] = hv.x; Hs[f + 1][bb] = hv.y;
        Hs[f + 2][bb] = hv.z; Hs[f + 3][bb] = hv.w;
      }
      __syncthreads();
    }
  }
}

// ---------------------------------------------------------------------------
extern "C" void kernel_launch(void* const* d_in, const int* in_sizes, int n_in,
                              void* d_out, int out_size, void* d_ws, size_t ws_size,
                              hipStream_t stream) {
  const float* x     = (const float*)d_in[0];
  const float* h0    = (const float*)d_in[1];
  const float* Wih_w = (const float*)d_in[2];
  const float* Wih_b = (const float*)d_in[3];
  const float* Whh_w = (const float*)d_in[4];
  const float* Whh_b = (const float*)d_in[5];

  float* y     = (float*)d_out;
  float* hlast = y + (size_t)B * S * H;
  float* P     = (float*)d_ws;   // KS*B*H floats = 4 MB

  gemm_nt<<<dim3(H / 64, (B * S) / 64), 256, 0, stream>>>(x, Wih_w, Wih_b, y);

  void* args[] = {(void*)&h0, (void*)&Whh_w, (void*)&Whh_b,
                  (void*)&y, (void*)&hlast, (void*)&P};
  hipLaunchCooperativeKernel((const void*)rnn_scan, dim3(256), dim3(256),
                             args, 0, stream);
}